// Round 5
// baseline (436.832 us; speedup 1.0000x reference)
//
#include <hip/hip_runtime.h>
#include <stdint.h>
#include <stddef.h>

typedef __attribute__((ext_vector_type(8))) short short8;
typedef __attribute__((ext_vector_type(4))) float f32x4;

// ---- sizes ----
// x: (8, 64, 32, 32, 96) f32.  NH=4, hd=16, scale = 0.25
// intermediates q,k,v: bf16, per (b,o): layout [ch=d/8][pos][dl=d%8], pos = h*32+w for ALL of q,k,v
#define PER_BO 98304            // 12 * 8192 ushorts per (b,o)
#define CSTRIDE 8192            // 1024 pos * 8 dl

__device__ __forceinline__ unsigned short f2bf(float f) {
    union { float f; unsigned int u; } v; v.f = f;
    unsigned int r = (v.u + 0x7FFFu + ((v.u >> 16) & 1u)) >> 16;
    return (unsigned short)r;
}

__device__ __forceinline__ unsigned int cvtpk(float lo, float hi) {
    unsigned int r;
    asm("v_cvt_pk_bf16_f32 %0, %1, %2" : "=v"(r) : "v"(lo), "v"(hi));
    return r;
}

// ============================ Kernel 1: projection GEMM (MFMA) ============================
// C[192 pos, 192 out] per block (2 hw columns). x staged into LDS [c][pos] f32 via
// global_load_lds (16B/lane, fully coalesced, no VGPR round-trip). Transpose happens on the
// LDS read side (8x ds_read_b32 per frag-half, 768B stride). hi/lo bf16 split in registers
// via v_cvt_pk_bf16_f32. W_eff bf16 in LDS (swizzled). One barrier.
__global__ __launch_bounds__(256, 2) void proj_mfma(
    const float* __restrict__ x, const float* __restrict__ w_sr, const float* __restrict__ b_sr,
    const float* __restrict__ Wq, const float* __restrict__ bq,
    const float* __restrict__ Wkv, const float* __restrict__ bkv,
    unsigned short* __restrict__ qb, unsigned short* __restrict__ kb, unsigned short* __restrict__ vb)
{
    __shared__ float Xs[12288];            // [64 c][192 pos] f32, 48 KB
    __shared__ unsigned short Wh[12288];   // 24.6 KB
    __shared__ float bl[192];

    int t = threadIdx.x;
    int bidx = blockIdx.x;
    int b = bidx >> 9;                 // 8 batches x 512 blocks
    int blk = bidx & 511;

    int lane = t & 63;
    int wvi = t >> 6;                  // 0..3; wave owns pos-tiles wvi*3 .. wvi*3+2
    int lr = lane & 15, hk = lane >> 4;

    // ---- async-stage x slab (16B chunks, contiguous 1KB per wave-instruction) ----
    const float* xb = x + (size_t)b * 6291456 + (size_t)blk * 192;
#pragma unroll
    for (int i = 0; i < 12; ++i) {
        int s = i * 256 + t;               // chunk index, 3072 total
        int c = s / 48;
        int pq = s - c * 48;
        const float* g = xb + (size_t)c * 98304 + pq * 4;
        float* l = &Xs[(i * 256 + (t & 192)) * 4];   // wave-uniform LDS base; HW adds lane*16
        __builtin_amdgcn_global_load_lds(
            (const __attribute__((address_space(1))) unsigned int*)g,
            (__attribute__((address_space(3))) unsigned int*)l, 16, 0, 0);
    }

    // ---- stage W_eff (bf16, swizzled): element (o,c) -> Wh[o*64 + ((c>>3)^(o&7))*8 + (c&7)] ----
#pragma unroll
    for (int i = 0; i < 12; ++i) {
        int qi = t + i * 256;          // quad index, 3072 total
        int o = qi >> 4;
        int cq = qi & 15;              // c = cq*4
        int c = cq * 4;
        float4 wv4;
        if (o < 64) wv4 = *reinterpret_cast<const float4*>(Wq + o * 64 + c);
        else {
            wv4 = *reinterpret_cast<const float4*>(Wkv + (o - 64) * 64 + c);
            float4 sr = *reinterpret_cast<const float4*>(w_sr + c);
            wv4.x *= sr.x; wv4.y *= sr.y; wv4.z *= sr.z; wv4.w *= sr.w;
        }
        uint2 pk; pk.x = cvtpk(wv4.x, wv4.y); pk.y = cvtpk(wv4.z, wv4.w);
        int sw = (cq >> 1) ^ (o & 7);
        *reinterpret_cast<uint2*>(&Wh[o * 64 + sw * 8 + (cq & 1) * 4]) = pk;
    }
    if (t < 192) {
        float s;
        if (t < 64) s = bq[t];
        else {
            s = bkv[t - 64];
            for (int c = 0; c < 64; ++c) s += Wkv[(t - 64) * 64 + c] * b_sr[c];
        }
        bl[t] = s;
    }
    __syncthreads();

    // ---- frag build: read transposed from Xs, split hi/lo in regs ----
    short8 ahf[3][2], alf[3][2];
#pragma unroll
    for (int pi = 0; pi < 3; ++pi) {
        int pos = (wvi * 3 + pi) * 16 + lr;
#pragma unroll
        for (int hf = 0; hf < 2; ++hf) {
            const float* xr = &Xs[(hf * 32 + hk * 8) * 192 + pos];
            union { unsigned int u[4]; short8 v; } H, L;
#pragma unroll
            for (int q = 0; q < 4; ++q) {
                float f0 = xr[(2 * q) * 192];
                float f1 = xr[(2 * q + 1) * 192];
                unsigned int hp = cvtpk(f0, f1);
                float h0 = __uint_as_float(hp << 16);
                float h1 = __uint_as_float(hp & 0xffff0000u);
                H.u[q] = hp;
                L.u[q] = cvtpk(f0 - h0, f1 - h1);
            }
            ahf[pi][hf] = H.v; alf[pi][hf] = L.v;
        }
    }

    // ---- per-pt store offsets (same layout for q,k,v) ----
    size_t offs[3];
#pragma unroll
    for (int pi = 0; pi < 3; ++pi) {
        int p0 = (wvi * 3 + pi) * 16 + hk * 4;
        int hwl = p0 / 96;
        int d = p0 - hwl * 96;
        int ch = d >> 3, dlb = d & 7;
        int hw = blk * 2 + hwl;
        offs[pi] = (size_t)ch * CSTRIDE + (size_t)hw * 8 + dlb;
    }

    float biasv[12];
#pragma unroll
    for (int ot = 0; ot < 12; ++ot) biasv[ot] = bl[ot * 16 + lr];

    f32x4 zero4 = {0.f, 0.f, 0.f, 0.f};
    int s7 = lr & 7;

    // ---- main loop: ot outer (B-frags read once), pt inner (A resident) ----
#pragma unroll
    for (int ot = 0; ot < 12; ++ot) {
        int o = ot * 16 + lr;
        const unsigned short* wr = &Wh[o * 64];
        short8 b0 = *reinterpret_cast<const short8*>(wr + ((hk ^ s7) * 8));
        short8 b1 = *reinterpret_cast<const short8*>(wr + (((hk + 4) ^ s7) * 8));
        float bo = biasv[ot];
        unsigned short* basep;
        if (ot < 4)       basep = qb + (size_t)(b * 64 + o) * PER_BO;
        else if (ot < 8)  basep = kb + (size_t)(b * 64 + (o - 64)) * PER_BO;
        else              basep = vb + (size_t)(b * 64 + (o - 128)) * PER_BO;
#pragma unroll
        for (int pi = 0; pi < 3; ++pi) {
            f32x4 acc = __builtin_amdgcn_mfma_f32_16x16x32_bf16(ahf[pi][0], b0, zero4, 0, 0, 0);
            acc = __builtin_amdgcn_mfma_f32_16x16x32_bf16(ahf[pi][1], b1, acc, 0, 0, 0);
            acc = __builtin_amdgcn_mfma_f32_16x16x32_bf16(alf[pi][0], b0, acc, 0, 0, 0);
            acc = __builtin_amdgcn_mfma_f32_16x16x32_bf16(alf[pi][1], b1, acc, 0, 0, 0);
            uint2 st;
            st.x = cvtpk(acc[0] + bo, acc[1] + bo);
            st.y = cvtpk(acc[2] + bo, acc[3] + bo);
            *reinterpret_cast<uint2*>(basep + offs[pi]) = st;
        }
    }
}

// ============================ Kernel 2: attention ============================
// one block per (b, n, c) triple. 1024 threads = 16 waves = 4 (h,g)-tiles x 4 d-subgroups.
// v is h-major in global; transpose happens in the Vs staging addressing:
// Vs[dl][j][g], row stride 36 ushorts, plane stride 1152.
__global__ __launch_bounds__(1024, 4) void attn_kernel(
    const unsigned short* __restrict__ qb, const unsigned short* __restrict__ kb,
    const unsigned short* __restrict__ vb,
    const float* __restrict__ gamma, const float* __restrict__ beta,
    float* __restrict__ out)
{
    extern __shared__ char smem[];
    unsigned short* Qs = (unsigned short*)smem;
    unsigned short* Ks = (unsigned short*)(smem + 20480);
    unsigned short* Vs = (unsigned short*)(smem + 40960);
    unsigned short* Ps = (unsigned short*)(smem + 61440);
    float* Os = (float*)(smem + 71680);
    float* lred = (float*)(smem + 40960);

    int t = threadIdx.x;
    int l = t & 63;
    int wv = t >> 6;
    int tile = wv & 3;
    int hb = tile >> 1, gb = tile & 1;
    int dsub = wv >> 2;
    int lr = l & 15, lk = l >> 4;

    int id = blockIdx.x;
    int b = id >> 6;
    int n = (id >> 4) & 3;
    int oc = id & 63;   // n*16 + c

    const unsigned short* qp = qb + (size_t)(b * 64 + oc) * PER_BO;
    const unsigned short* kp = kb + (size_t)(b * 64 + oc) * PER_BO;
    const unsigned short* vp = vb + (size_t)(b * 64 + oc) * PER_BO;

    float gm = gamma[n], bt = beta[n];
    float decv[4];
#pragma unroll
    for (int r = 0; r < 4; ++r) {
        int hh = hb * 16 + lk * 4 + r;
        int gg = gb * 16 + lr;
        float dc = 2.0f * fabsf((float)(hh - gg)) * gm + bt;
        float sp = fmaxf(dc, 0.0f) + log1pf(__expf(-fabsf(dc)));
        decv[r] = __expf(-sp);
    }

    const float scale = 0.25f;
    f32x4 zero4 = {0.f, 0.f, 0.f, 0.f};
    float lacc[4] = {0.f, 0.f, 0.f, 0.f};

    int qfoff = (hb * 16 + lr) * 40 + lk * 8;
    int kfoff = (gb * 16 + lr) * 40 + lk * 8;
    int stage_base = (t >> 5) * 40 + (t & 31);

    // ---------------- PASS 1: denominators ----------------
    for (int ch = 0; ch < 12; ++ch) {
        __syncthreads();
        {
            uint4 uq = *reinterpret_cast<const uint4*>(qp + (size_t)ch * CSTRIDE + t * 8);
            uint4 uk = *reinterpret_cast<const uint4*>(kp + (size_t)ch * CSTRIDE + t * 8);
            const unsigned short* sq = (const unsigned short*)&uq;
            const unsigned short* sk = (const unsigned short*)&uk;
#pragma unroll
            for (int i = 0; i < 8; ++i) {
                Qs[i * 1280 + stage_base] = sq[i];
                Ks[i * 1280 + stage_base] = sk[i];
            }
        }
        __syncthreads();
#pragma unroll
        for (int rr = 0; rr < 2; ++rr) {
            int dl = dsub * 2 + rr;
            short8 a  = *reinterpret_cast<const short8*>(&Qs[dl * 1280 + qfoff]);
            short8 bf = *reinterpret_cast<const short8*>(&Ks[dl * 1280 + kfoff]);
            f32x4 s = __builtin_amdgcn_mfma_f32_16x16x32_bf16(a, bf, zero4, 0, 0, 0);
#pragma unroll
            for (int r = 0; r < 4; ++r)
                lacc[r] += __expf(s[r] * scale + decv[r]);
        }
    }
    __syncthreads();
#pragma unroll
    for (int r = 0; r < 4; ++r)
        lred[dsub * 1056 + (hb * 16 + lk * 4 + r) * 33 + gb * 16 + lr] = lacc[r];
    __syncthreads();
    float rl[4];
#pragma unroll
    for (int r = 0; r < 4; ++r) {
        int idx = (hb * 16 + lk * 4 + r) * 33 + gb * 16 + lr;
        float sum = lred[idx] + lred[1056 + idx] + lred[2112 + idx] + lred[3168 + idx];
        rl[r] = 1.0f / sum;
    }

    // ---------------- PASS 2: P and O ----------------
    int pfoff = (hb * 16 + lr) * 40 + lk * 8;
    int vfoff = (gb * 16 + lr) * 36 + lk * 8;   // Vs[dl][j][g], row stride 36

    for (int c2 = 0; c2 < 6; ++c2) {
        for (int sub = 0; sub < 2; ++sub) {
            int ch = c2 * 2 + sub;
            __syncthreads();
            {
                uint4 uq = *reinterpret_cast<const uint4*>(qp + (size_t)ch * CSTRIDE + t * 8);
                uint4 uk = *reinterpret_cast<const uint4*>(kp + (size_t)ch * CSTRIDE + t * 8);
                uint4 uv = *reinterpret_cast<const uint4*>(vp + (size_t)ch * CSTRIDE + t * 8);
                const unsigned short* sq = (const unsigned short*)&uq;
                const unsigned short* sk = (const unsigned short*)&uk;
                const unsigned short* sv = (const unsigned short*)&uv;
                int vtr = (t & 31) * 36 + (t >> 5);   // transpose: row j = w, col g = h
#pragma unroll
                for (int i = 0; i < 8; ++i) {
                    Qs[i * 1280 + stage_base] = sq[i];
                    Ks[i * 1280 + stage_base] = sk[i];
                    Vs[i * 1152 + vtr] = sv[i];
                }
            }
            __syncthreads();
            for (int rr = 0; rr < 2; ++rr) {
                int dl = dsub * 2 + rr;
                short8 a  = *reinterpret_cast<const short8*>(&Qs[dl * 1280 + qfoff]);
                short8 bf = *reinterpret_cast<const short8*>(&Ks[dl * 1280 + kfoff]);
                f32x4 s = __builtin_amdgcn_mfma_f32_16x16x32_bf16(a, bf, zero4, 0, 0, 0);
#pragma unroll
                for (int r = 0; r < 4; ++r) {
                    float pv = __expf(s[r] * scale + decv[r]) * rl[r];
                    Ps[dsub * 1280 + (hb * 16 + lk * 4 + r) * 40 + gb * 16 + lr] = f2bf(pv);
                }
                __syncthreads();
                short8 pa  = *reinterpret_cast<const short8*>(&Ps[dsub * 1280 + pfoff]);
                short8 vbf = *reinterpret_cast<const short8*>(&Vs[dl * 1152 + vfoff]);
                f32x4 o4 = __builtin_amdgcn_mfma_f32_16x16x32_bf16(pa, vbf, zero4, 0, 0, 0);
#pragma unroll
                for (int r = 0; r < 4; ++r)
                    Os[(sub * 8 + dl) * 1056 + (hb * 16 + lk * 4 + r) * 33 + gb * 16 + lr] = o4[r];
                __syncthreads();
            }
        }
        {
            size_t obase = ((size_t)(b * 64 + oc) * 1024 + t) * 96 + c2 * 16;
            int lidx = t + (t >> 5);
#pragma unroll
            for (int q2 = 0; q2 < 4; ++q2) {
                float4 ov;
                ov.x = Os[(q2 * 4 + 0) * 1056 + lidx];
                ov.y = Os[(q2 * 4 + 1) * 1056 + lidx];
                ov.z = Os[(q2 * 4 + 2) * 1056 + lidx];
                ov.w = Os[(q2 * 4 + 3) * 1056 + lidx];
                *reinterpret_cast<float4*>(out + obase + q2 * 4) = ov;
            }
        }
    }
}

extern "C" void kernel_launch(void* const* d_in, const int* in_sizes, int n_in,
                              void* d_out, int out_size, void* d_ws, size_t ws_size,
                              hipStream_t stream) {
    const float* x     = (const float*)d_in[0];
    const float* w_sr  = (const float*)d_in[1];
    const float* b_sr  = (const float*)d_in[2];
    const float* Wq    = (const float*)d_in[3];
    const float* bq    = (const float*)d_in[4];
    const float* Wkv   = (const float*)d_in[5];
    const float* bkv   = (const float*)d_in[6];
    const float* gamma = (const float*)d_in[7];
    const float* beta  = (const float*)d_in[8];
    float* out = (float*)d_out;

    unsigned short* qb = (unsigned short*)d_ws;
    unsigned short* kb = qb + (size_t)50331648;
    unsigned short* vb = kb + (size_t)50331648;

    proj_mfma<<<4096, 256, 0, stream>>>(x, w_sr, b_sr, Wq, bq, Wkv, bkv, qb, kb, vb);

    (void)hipFuncSetAttribute(reinterpret_cast<const void*>(attn_kernel),
                              hipFuncAttributeMaxDynamicSharedMemorySize, 139264);
    attn_kernel<<<512, 1024, 139264, stream>>>(qb, kb, vb, gamma, beta, out);
}

// Round 6
// 349.356 us; speedup vs baseline: 1.2504x; 1.2504x over previous
//
#include <hip/hip_runtime.h>
#include <stdint.h>
#include <stddef.h>

typedef __attribute__((ext_vector_type(8))) short short8;
typedef __attribute__((ext_vector_type(4))) float f32x4;

// ---- sizes ----
// x: (8, 64, 32, 32, 96) f32.  NH=4, hd=16, scale = 0.25
// intermediates q,k,v: bf16, per (b,o): layout [ch=d/8][pos][dl=d%8], pos = h*32+w for ALL of q,k,v
#define PER_BO 98304            // 12 * 8192 ushorts per (b,o)
#define CSTRIDE 8192            // 1024 pos * 8 dl

__device__ __forceinline__ unsigned short f2bf(float f) {
    union { float f; unsigned int u; } v; v.f = f;
    unsigned int r = (v.u + 0x7FFFu + ((v.u >> 16) & 1u)) >> 16;
    return (unsigned short)r;
}

__device__ __forceinline__ unsigned int cvtpk(float lo, float hi) {
    unsigned int r;
    asm("v_cvt_pk_bf16_f32 %0, %1, %2" : "=v"(r) : "v"(lo), "v"(hi));
    return r;
}

// ============================ Kernel 1: projection GEMM (MFMA) ============================
// C[384 pos, 192 out] per block (4 hw columns, 512 threads, 8 waves, 3 pos-tiles/wave).
// A (x) loaded direct to regs in fragment layout, hi/lo bf16 split (cvt_pk). W bf16 in LDS
// (swizzled). C routed through LDS double-buffer so global stores are emitted as
// 8 full 64B-line segments per wave-op (vs 32 scattered 16B segments direct).
__global__ __launch_bounds__(512, 2) void proj_mfma(
    const float* __restrict__ x, const float* __restrict__ w_sr, const float* __restrict__ b_sr,
    const float* __restrict__ Wq, const float* __restrict__ bq,
    const float* __restrict__ Wkv, const float* __restrict__ bkv,
    unsigned short* __restrict__ qb, unsigned short* __restrict__ kb, unsigned short* __restrict__ vb)
{
    __shared__ unsigned short Wh[12288];      // 24.6 KB
    __shared__ float bl[192];
    __shared__ unsigned short Cb[2 * 6464];   // 25.9 KB: [buf][o:404][hwl:100][d]

    int t = threadIdx.x;
    int bidx = blockIdx.x;
    int b = bidx >> 8;                 // 8 batches x 256 blocks
    int blk = bidx & 255;              // 4 hw columns each

    int lane = t & 63;
    int wvi = t >> 6;                  // 0..7; wave owns pos-tiles wvi*3 .. wvi*3+2
    int lr = lane & 15, hk = lane >> 4;

    // ---- A: load x straight into registers (fragment layout), issue first ----
    const float* xb = x + (size_t)b * 6291456 + (size_t)blk * 384;
    float af[3][16];
#pragma unroll
    for (int pi = 0; pi < 3; ++pi) {
        int pt = wvi * 3 + pi;
        const float* xp = xb + (size_t)(hk * 8) * 98304 + pt * 16 + lr;
#pragma unroll
        for (int j = 0; j < 8; ++j) {
            af[pi][j]     = xp[(size_t)j * 98304];
            af[pi][8 + j] = xp[(size_t)(32 + j) * 98304];
        }
    }

    // ---- stage W_eff (bf16, swizzled): element (o,c) -> Wh[o*64 + ((c>>3)^(o&7))*8 + (c&7)] ----
#pragma unroll
    for (int i = 0; i < 6; ++i) {
        int qi = t + i * 512;          // quad index, 3072 total
        int o = qi >> 4;
        int cq = qi & 15;              // c = cq*4
        int c = cq * 4;
        float4 wv4;
        if (o < 64) wv4 = *reinterpret_cast<const float4*>(Wq + o * 64 + c);
        else {
            wv4 = *reinterpret_cast<const float4*>(Wkv + (o - 64) * 64 + c);
            float4 sr = *reinterpret_cast<const float4*>(w_sr + c);
            wv4.x *= sr.x; wv4.y *= sr.y; wv4.z *= sr.z; wv4.w *= sr.w;
        }
        uint2 pk; pk.x = cvtpk(wv4.x, wv4.y); pk.y = cvtpk(wv4.z, wv4.w);
        int sw = (cq >> 1) ^ (o & 7);
        *reinterpret_cast<uint2*>(&Wh[o * 64 + sw * 8 + (cq & 1) * 4]) = pk;
    }
    if (t < 192) {
        float s;
        if (t < 64) s = bq[t];
        else {
            s = bkv[t - 64];
            for (int c = 0; c < 64; ++c) s += Wkv[(t - 64) * 64 + c] * b_sr[c];
        }
        bl[t] = s;
    }
    __syncthreads();

    // ---- convert A to hi/lo bf16 fragments (cvt_pk) ----
    short8 ahf[3][2], alf[3][2];
#pragma unroll
    for (int pi = 0; pi < 3; ++pi) {
#pragma unroll
        for (int half = 0; half < 2; ++half) {
            union { unsigned int u[4]; short8 v; } H, L;
#pragma unroll
            for (int q = 0; q < 4; ++q) {
                float f0 = af[pi][half * 8 + 2 * q];
                float f1 = af[pi][half * 8 + 2 * q + 1];
                unsigned int hp = cvtpk(f0, f1);
                float h0 = __uint_as_float(hp << 16);
                float h1 = __uint_as_float(hp & 0xffff0000u);
                H.u[q] = hp;
                L.u[q] = cvtpk(f0 - h0, f1 - h1);
            }
            ahf[pi][half] = H.v; alf[pi][half] = L.v;
        }
    }

    // ---- per-pt LDS C-write offsets: Cb[o=lr][hwl][d0..d0+3] ----
    int wo[3];
#pragma unroll
    for (int pi = 0; pi < 3; ++pi) {
        int p0 = (wvi * 3 + pi) * 16 + hk * 4;
        int hwl = p0 / 96;
        int d0 = p0 - hwl * 96;
        wo[pi] = lr * 404 + hwl * 100 + d0;
    }

    // ---- stream-out decode (per thread, 3 chunks of uint2 = 4 shorts) ----
    // flat ordered (o, ch, hwl, dlq) so consecutive lanes -> consecutive global addrs.
    int so_po[3], so_lo[3];
#pragma unroll
    for (int i = 0; i < 3; ++i) {
        int flat = i * 512 + t;        // 0..1535
        int dlq = flat & 1;
        int hwl = (flat >> 1) & 3;
        int ch  = (flat >> 3) % 12;
        int o   = flat / 96;
        so_po[i] = o * PER_BO + ch * 8192 + (blk * 4 + hwl) * 8 + dlq * 4;
        so_lo[i] = o * 404 + hwl * 100 + ch * 8 + dlq * 4;
    }

    float biasv[12];
#pragma unroll
    for (int ot = 0; ot < 12; ++ot) biasv[ot] = bl[ot * 16 + lr];

    f32x4 zero4 = {0.f, 0.f, 0.f, 0.f};
    int s7 = lr & 7;

    // ---- main loop: ot outer; compute -> LDS C tile -> coalesced stream-out ----
#pragma unroll
    for (int ot = 0; ot < 12; ++ot) {
        unsigned short* cb = Cb + (ot & 1) * 6464;
        {
            int o = ot * 16 + lr;
            const unsigned short* wr = &Wh[o * 64];
            short8 b0 = *reinterpret_cast<const short8*>(wr + ((hk ^ s7) * 8));
            short8 b1 = *reinterpret_cast<const short8*>(wr + (((hk + 4) ^ s7) * 8));
            float bo = biasv[ot];
#pragma unroll
            for (int pi = 0; pi < 3; ++pi) {
                f32x4 acc = __builtin_amdgcn_mfma_f32_16x16x32_bf16(ahf[pi][0], b0, zero4, 0, 0, 0);
                acc = __builtin_amdgcn_mfma_f32_16x16x32_bf16(ahf[pi][1], b1, acc, 0, 0, 0);
                acc = __builtin_amdgcn_mfma_f32_16x16x32_bf16(alf[pi][0], b0, acc, 0, 0, 0);
                acc = __builtin_amdgcn_mfma_f32_16x16x32_bf16(alf[pi][1], b1, acc, 0, 0, 0);
                uint2 st;
                st.x = cvtpk(acc[0] + bo, acc[1] + bo);
                st.y = cvtpk(acc[2] + bo, acc[3] + bo);
                *reinterpret_cast<uint2*>(&cb[wo[pi]]) = st;
            }
        }
        __syncthreads();
        {
            int sel = ot >> 2;
            unsigned short* base =
                (sel == 0 ? qb : (sel == 1 ? kb : vb)) + (size_t)(b * 64 + (ot & 3) * 16) * PER_BO;
#pragma unroll
            for (int i = 0; i < 3; ++i)
                *reinterpret_cast<uint2*>(base + so_po[i]) =
                    *reinterpret_cast<const uint2*>(&cb[so_lo[i]]);
        }
    }
}

// ============================ Kernel 2: attention ============================
// one block per (b, n, c) triple. 1024 threads = 16 waves = 4 (h,g)-tiles x 4 d-subgroups.
// v is h-major in global; transpose happens in the Vs staging addressing:
// Vs[dl][j][g], row stride 36 ushorts, plane stride 1152.
__global__ __launch_bounds__(1024, 4) void attn_kernel(
    const unsigned short* __restrict__ qb, const unsigned short* __restrict__ kb,
    const unsigned short* __restrict__ vb,
    const float* __restrict__ gamma, const float* __restrict__ beta,
    float* __restrict__ out)
{
    extern __shared__ char smem[];
    unsigned short* Qs = (unsigned short*)smem;
    unsigned short* Ks = (unsigned short*)(smem + 20480);
    unsigned short* Vs = (unsigned short*)(smem + 40960);
    unsigned short* Ps = (unsigned short*)(smem + 61440);
    float* Os = (float*)(smem + 71680);
    float* lred = (float*)(smem + 40960);

    int t = threadIdx.x;
    int l = t & 63;
    int wv = t >> 6;
    int tile = wv & 3;
    int hb = tile >> 1, gb = tile & 1;
    int dsub = wv >> 2;
    int lr = l & 15, lk = l >> 4;

    int id = blockIdx.x;
    int b = id >> 6;
    int n = (id >> 4) & 3;
    int oc = id & 63;   // n*16 + c

    const unsigned short* qp = qb + (size_t)(b * 64 + oc) * PER_BO;
    const unsigned short* kp = kb + (size_t)(b * 64 + oc) * PER_BO;
    const unsigned short* vp = vb + (size_t)(b * 64 + oc) * PER_BO;

    float gm = gamma[n], bt = beta[n];
    float decv[4];
#pragma unroll
    for (int r = 0; r < 4; ++r) {
        int hh = hb * 16 + lk * 4 + r;
        int gg = gb * 16 + lr;
        float dc = 2.0f * fabsf((float)(hh - gg)) * gm + bt;
        float sp = fmaxf(dc, 0.0f) + log1pf(__expf(-fabsf(dc)));
        decv[r] = __expf(-sp);
    }

    const float scale = 0.25f;
    f32x4 zero4 = {0.f, 0.f, 0.f, 0.f};
    float lacc[4] = {0.f, 0.f, 0.f, 0.f};

    int qfoff = (hb * 16 + lr) * 40 + lk * 8;
    int kfoff = (gb * 16 + lr) * 40 + lk * 8;
    int stage_base = (t >> 5) * 40 + (t & 31);

    // ---------------- PASS 1: denominators ----------------
    for (int ch = 0; ch < 12; ++ch) {
        __syncthreads();
        {
            uint4 uq = *reinterpret_cast<const uint4*>(qp + (size_t)ch * CSTRIDE + t * 8);
            uint4 uk = *reinterpret_cast<const uint4*>(kp + (size_t)ch * CSTRIDE + t * 8);
            const unsigned short* sq = (const unsigned short*)&uq;
            const unsigned short* sk = (const unsigned short*)&uk;
#pragma unroll
            for (int i = 0; i < 8; ++i) {
                Qs[i * 1280 + stage_base] = sq[i];
                Ks[i * 1280 + stage_base] = sk[i];
            }
        }
        __syncthreads();
#pragma unroll
        for (int rr = 0; rr < 2; ++rr) {
            int dl = dsub * 2 + rr;
            short8 a  = *reinterpret_cast<const short8*>(&Qs[dl * 1280 + qfoff]);
            short8 bf = *reinterpret_cast<const short8*>(&Ks[dl * 1280 + kfoff]);
            f32x4 s = __builtin_amdgcn_mfma_f32_16x16x32_bf16(a, bf, zero4, 0, 0, 0);
#pragma unroll
            for (int r = 0; r < 4; ++r)
                lacc[r] += __expf(s[r] * scale + decv[r]);
        }
    }
    __syncthreads();
#pragma unroll
    for (int r = 0; r < 4; ++r)
        lred[dsub * 1056 + (hb * 16 + lk * 4 + r) * 33 + gb * 16 + lr] = lacc[r];
    __syncthreads();
    float rl[4];
#pragma unroll
    for (int r = 0; r < 4; ++r) {
        int idx = (hb * 16 + lk * 4 + r) * 33 + gb * 16 + lr;
        float sum = lred[idx] + lred[1056 + idx] + lred[2112 + idx] + lred[3168 + idx];
        rl[r] = 1.0f / sum;
    }

    // ---------------- PASS 2: P and O ----------------
    int pfoff = (hb * 16 + lr) * 40 + lk * 8;
    int vfoff = (gb * 16 + lr) * 36 + lk * 8;   // Vs[dl][j][g], row stride 36

    for (int c2 = 0; c2 < 6; ++c2) {
        for (int sub = 0; sub < 2; ++sub) {
            int ch = c2 * 2 + sub;
            __syncthreads();
            {
                uint4 uq = *reinterpret_cast<const uint4*>(qp + (size_t)ch * CSTRIDE + t * 8);
                uint4 uk = *reinterpret_cast<const uint4*>(kp + (size_t)ch * CSTRIDE + t * 8);
                uint4 uv = *reinterpret_cast<const uint4*>(vp + (size_t)ch * CSTRIDE + t * 8);
                const unsigned short* sq = (const unsigned short*)&uq;
                const unsigned short* sk = (const unsigned short*)&uk;
                const unsigned short* sv = (const unsigned short*)&uv;
                int vtr = (t & 31) * 36 + (t >> 5);   // transpose: row j = w, col g = h
#pragma unroll
                for (int i = 0; i < 8; ++i) {
                    Qs[i * 1280 + stage_base] = sq[i];
                    Ks[i * 1280 + stage_base] = sk[i];
                    Vs[i * 1152 + vtr] = sv[i];
                }
            }
            __syncthreads();
            for (int rr = 0; rr < 2; ++rr) {
                int dl = dsub * 2 + rr;
                short8 a  = *reinterpret_cast<const short8*>(&Qs[dl * 1280 + qfoff]);
                short8 bf = *reinterpret_cast<const short8*>(&Ks[dl * 1280 + kfoff]);
                f32x4 s = __builtin_amdgcn_mfma_f32_16x16x32_bf16(a, bf, zero4, 0, 0, 0);
#pragma unroll
                for (int r = 0; r < 4; ++r) {
                    float pv = __expf(s[r] * scale + decv[r]) * rl[r];
                    Ps[dsub * 1280 + (hb * 16 + lk * 4 + r) * 40 + gb * 16 + lr] = f2bf(pv);
                }
                __syncthreads();
                short8 pa  = *reinterpret_cast<const short8*>(&Ps[dsub * 1280 + pfoff]);
                short8 vbf = *reinterpret_cast<const short8*>(&Vs[dl * 1152 + vfoff]);
                f32x4 o4 = __builtin_amdgcn_mfma_f32_16x16x32_bf16(pa, vbf, zero4, 0, 0, 0);
#pragma unroll
                for (int r = 0; r < 4; ++r)
                    Os[(sub * 8 + dl) * 1056 + (hb * 16 + lk * 4 + r) * 33 + gb * 16 + lr] = o4[r];
                __syncthreads();
            }
        }
        {
            size_t obase = ((size_t)(b * 64 + oc) * 1024 + t) * 96 + c2 * 16;
            int lidx = t + (t >> 5);
#pragma unroll
            for (int q2 = 0; q2 < 4; ++q2) {
                float4 ov;
                ov.x = Os[(q2 * 4 + 0) * 1056 + lidx];
                ov.y = Os[(q2 * 4 + 1) * 1056 + lidx];
                ov.z = Os[(q2 * 4 + 2) * 1056 + lidx];
                ov.w = Os[(q2 * 4 + 3) * 1056 + lidx];
                *reinterpret_cast<float4*>(out + obase + q2 * 4) = ov;
            }
        }
    }
}

extern "C" void kernel_launch(void* const* d_in, const int* in_sizes, int n_in,
                              void* d_out, int out_size, void* d_ws, size_t ws_size,
                              hipStream_t stream) {
    const float* x     = (const float*)d_in[0];
    const float* w_sr  = (const float*)d_in[1];
    const float* b_sr  = (const float*)d_in[2];
    const float* Wq    = (const float*)d_in[3];
    const float* bq    = (const float*)d_in[4];
    const float* Wkv   = (const float*)d_in[5];
    const float* bkv   = (const float*)d_in[6];
    const float* gamma = (const float*)d_in[7];
    const float* beta  = (const float*)d_in[8];
    float* out = (float*)d_out;

    unsigned short* qb = (unsigned short*)d_ws;
    unsigned short* kb = qb + (size_t)50331648;
    unsigned short* vb = kb + (size_t)50331648;

    proj_mfma<<<2048, 512, 0, stream>>>(x, w_sr, b_sr, Wq, bq, Wkv, bkv, qb, kb, vb);

    (void)hipFuncSetAttribute(reinterpret_cast<const void*>(attn_kernel),
                              hipFuncAttributeMaxDynamicSharedMemorySize, 139264);
    attn_kernel<<<512, 1024, 139264, stream>>>(qb, kb, vb, gamma, beta, out);
}

// Round 7
// 346.344 us; speedup vs baseline: 1.2613x; 1.0087x over previous
//
#include <hip/hip_runtime.h>
#include <stdint.h>
#include <stddef.h>

typedef __attribute__((ext_vector_type(8))) short short8;
typedef __attribute__((ext_vector_type(4))) float f32x4;

// ---- sizes ----
// x: (8, 64, 32, 32, 96) f32.  NH=4, hd=16, scale = 0.25
// intermediates q,k,v: bf16, per (b,o): layout [ch=d/8][pos=h*32+w][dl=d%8]
#define PER_BO 98304            // 12 * 8192 ushorts per (b,o)
#define CSTRIDE 8192            // 1024 pos * 8 dl

__device__ __forceinline__ unsigned int cvtpk(float lo, float hi) {
    unsigned int r;
    asm("v_cvt_pk_bf16_f32 %0, %1, %2" : "=v"(r) : "v"(lo), "v"(hi));
    return r;
}

// ============================ Kernel 1: projection GEMM (MFMA) ============================
// (unchanged from round 6 — C routed through LDS, coalesced stream-out)
__global__ __launch_bounds__(512, 2) void proj_mfma(
    const float* __restrict__ x, const float* __restrict__ w_sr, const float* __restrict__ b_sr,
    const float* __restrict__ Wq, const float* __restrict__ bq,
    const float* __restrict__ Wkv, const float* __restrict__ bkv,
    unsigned short* __restrict__ qb, unsigned short* __restrict__ kb, unsigned short* __restrict__ vb)
{
    __shared__ unsigned short Wh[12288];
    __shared__ float bl[192];
    __shared__ unsigned short Cb[2 * 6464];

    int t = threadIdx.x;
    int bidx = blockIdx.x;
    int b = bidx >> 8;
    int blk = bidx & 255;

    int lane = t & 63;
    int wvi = t >> 6;
    int lr = lane & 15, hk = lane >> 4;

    const float* xb = x + (size_t)b * 6291456 + (size_t)blk * 384;
    float af[3][16];
#pragma unroll
    for (int pi = 0; pi < 3; ++pi) {
        int pt = wvi * 3 + pi;
        const float* xp = xb + (size_t)(hk * 8) * 98304 + pt * 16 + lr;
#pragma unroll
        for (int j = 0; j < 8; ++j) {
            af[pi][j]     = xp[(size_t)j * 98304];
            af[pi][8 + j] = xp[(size_t)(32 + j) * 98304];
        }
    }

#pragma unroll
    for (int i = 0; i < 6; ++i) {
        int qi = t + i * 512;
        int o = qi >> 4;
        int cq = qi & 15;
        int c = cq * 4;
        float4 wv4;
        if (o < 64) wv4 = *reinterpret_cast<const float4*>(Wq + o * 64 + c);
        else {
            wv4 = *reinterpret_cast<const float4*>(Wkv + (o - 64) * 64 + c);
            float4 sr = *reinterpret_cast<const float4*>(w_sr + c);
            wv4.x *= sr.x; wv4.y *= sr.y; wv4.z *= sr.z; wv4.w *= sr.w;
        }
        uint2 pk; pk.x = cvtpk(wv4.x, wv4.y); pk.y = cvtpk(wv4.z, wv4.w);
        int sw = (cq >> 1) ^ (o & 7);
        *reinterpret_cast<uint2*>(&Wh[o * 64 + sw * 8 + (cq & 1) * 4]) = pk;
    }
    if (t < 192) {
        float s;
        if (t < 64) s = bq[t];
        else {
            s = bkv[t - 64];
            for (int c = 0; c < 64; ++c) s += Wkv[(t - 64) * 64 + c] * b_sr[c];
        }
        bl[t] = s;
    }
    __syncthreads();

    short8 ahf[3][2], alf[3][2];
#pragma unroll
    for (int pi = 0; pi < 3; ++pi) {
#pragma unroll
        for (int half = 0; half < 2; ++half) {
            union { unsigned int u[4]; short8 v; } H, L;
#pragma unroll
            for (int q = 0; q < 4; ++q) {
                float f0 = af[pi][half * 8 + 2 * q];
                float f1 = af[pi][half * 8 + 2 * q + 1];
                unsigned int hp = cvtpk(f0, f1);
                float h0 = __uint_as_float(hp << 16);
                float h1 = __uint_as_float(hp & 0xffff0000u);
                H.u[q] = hp;
                L.u[q] = cvtpk(f0 - h0, f1 - h1);
            }
            ahf[pi][half] = H.v; alf[pi][half] = L.v;
        }
    }

    int wo[3];
#pragma unroll
    for (int pi = 0; pi < 3; ++pi) {
        int p0 = (wvi * 3 + pi) * 16 + hk * 4;
        int hwl = p0 / 96;
        int d0 = p0 - hwl * 96;
        wo[pi] = lr * 404 + hwl * 100 + d0;
    }

    int so_po[3], so_lo[3];
#pragma unroll
    for (int i = 0; i < 3; ++i) {
        int flat = i * 512 + t;
        int dlq = flat & 1;
        int hwl = (flat >> 1) & 3;
        int ch  = (flat >> 3) % 12;
        int o   = flat / 96;
        so_po[i] = o * PER_BO + ch * 8192 + (blk * 4 + hwl) * 8 + dlq * 4;
        so_lo[i] = o * 404 + hwl * 100 + ch * 8 + dlq * 4;
    }

    float biasv[12];
#pragma unroll
    for (int ot = 0; ot < 12; ++ot) biasv[ot] = bl[ot * 16 + lr];

    f32x4 zero4 = {0.f, 0.f, 0.f, 0.f};
    int s7 = lr & 7;

#pragma unroll
    for (int ot = 0; ot < 12; ++ot) {
        unsigned short* cb = Cb + (ot & 1) * 6464;
        {
            int o = ot * 16 + lr;
            const unsigned short* wr = &Wh[o * 64];
            short8 b0 = *reinterpret_cast<const short8*>(wr + ((hk ^ s7) * 8));
            short8 b1 = *reinterpret_cast<const short8*>(wr + (((hk + 4) ^ s7) * 8));
            float bo = biasv[ot];
#pragma unroll
            for (int pi = 0; pi < 3; ++pi) {
                f32x4 acc = __builtin_amdgcn_mfma_f32_16x16x32_bf16(ahf[pi][0], b0, zero4, 0, 0, 0);
                acc = __builtin_amdgcn_mfma_f32_16x16x32_bf16(ahf[pi][1], b1, acc, 0, 0, 0);
                acc = __builtin_amdgcn_mfma_f32_16x16x32_bf16(alf[pi][0], b0, acc, 0, 0, 0);
                acc = __builtin_amdgcn_mfma_f32_16x16x32_bf16(alf[pi][1], b1, acc, 0, 0, 0);
                uint2 st;
                st.x = cvtpk(acc[0] + bo, acc[1] + bo);
                st.y = cvtpk(acc[2] + bo, acc[3] + bo);
                *reinterpret_cast<uint2*>(&cb[wo[pi]]) = st;
            }
        }
        __syncthreads();
        {
            int sel = ot >> 2;
            unsigned short* base =
                (sel == 0 ? qb : (sel == 1 ? kb : vb)) + (size_t)(b * 64 + (ot & 3) * 16) * PER_BO;
#pragma unroll
            for (int i = 0; i < 3; ++i)
                *reinterpret_cast<uint2*>(base + so_po[i]) =
                    *reinterpret_cast<const uint2*>(&cb[so_lo[i]]);
        }
    }
}

// ============================ Kernel 2: attention (d-sliced waves) ============================
// Block = (b, oc, h-half): 1024 blocks x 512 threads (8 waves). Wave dsub owns depth dl=dsub
// of each chunk -> QK^T, E (kept in 48 packed-bf16 VGPRs), P, PV all wave-private.
// Only cross-wave op: l[h,g] reduction (3 barriers). Double-buffered staging, 2 blocks/CU.
// LDS (57344 B): pass1 Qs@0 (2x10240), Ks@20480 (2x18432);
//                reduction lred@0 (8x528 f32), rl@16896 (528 f32);
//                pass2 Vs@0 (2x18432), Os@36864 (8x528 f32; Pb aliases Os[dsub]).
__global__ __launch_bounds__(512, 4) void attn_kernel(
    const unsigned short* __restrict__ qb, const unsigned short* __restrict__ kb,
    const unsigned short* __restrict__ vb,
    const float* __restrict__ gamma, const float* __restrict__ beta,
    float* __restrict__ out)
{
    extern __shared__ char smem[];
    unsigned short* Qs = (unsigned short*)smem;
    unsigned short* Ks = (unsigned short*)(smem + 20480);
    float* lred = (float*)smem;
    float* rlb  = (float*)(smem + 16896);
    unsigned short* Vs = (unsigned short*)smem;
    float* Osf  = (float*)(smem + 36864);

    int t = threadIdx.x;
    int l = t & 63;
    int dsub = t >> 6;                 // wave id = owned dl
    int lr = l & 15, hk = l >> 4;

    int id = blockIdx.x;
    int half = id & 1;
    int oc = (id >> 1) & 63;
    int b = id >> 7;
    int n = oc >> 4;

    const unsigned short* qp = qb + (size_t)(b * 64 + oc) * PER_BO + half * 4096;
    const unsigned short* kp = kb + (size_t)(b * 64 + oc) * PER_BO;
    const unsigned short* vp = vb + (size_t)(b * 64 + oc) * PER_BO;

    float gm = gamma[n], bt = beta[n];
    float decv[8];                     // [gb*4 + r]
#pragma unroll
    for (int gb = 0; gb < 2; ++gb)
#pragma unroll
        for (int r = 0; r < 4; ++r) {
            int hh = half * 16 + hk * 4 + r;
            int gg = gb * 16 + lr;
            float dc = 2.0f * fabsf((float)(hh - gg)) * gm + bt;
            float sp = fmaxf(dc, 0.0f) + log1pf(__expf(-fabsf(dc)));
            decv[gb * 4 + r] = __expf(-sp);
        }

    const float scale = 0.25f;
    f32x4 zero4 = {0.f, 0.f, 0.f, 0.f};

    unsigned int ep[48];
    float lacc[8] = {0.f, 0.f, 0.f, 0.f, 0.f, 0.f, 0.f, 0.f};

    auto WRQ = [&](int buf, uint4 v) {
        const unsigned short* sq = (const unsigned short*)&v;
        int base = buf * 5120 + (t >> 5) * 40 + (t & 31);
#pragma unroll
        for (int i = 0; i < 8; ++i) Qs[base + i * 640] = sq[i];
    };
    auto WRK = [&](int buf, uint4 v0, uint4 v1) {
        const unsigned short* s0 = (const unsigned short*)&v0;
        const unsigned short* s1 = (const unsigned short*)&v1;
        int b0 = buf * 9216 + (t >> 5) * 36 + (t & 31);
        int b1 = buf * 9216 + ((t + 512) >> 5) * 36 + (t & 31);
#pragma unroll
        for (int i = 0; i < 8; ++i) { Ks[b0 + i * 1152] = s0[i]; Ks[b1 + i * 1152] = s1[i]; }
    };

    // ---------------- PASS 1: QK^T -> E (regs) + partial l ----------------
    uint4 qh  = *reinterpret_cast<const uint4*>(qp + t * 8);
    uint4 kh0 = *reinterpret_cast<const uint4*>(kp + t * 8);
    uint4 kh1 = *reinterpret_cast<const uint4*>(kp + (t + 512) * 8);
    WRQ(0, qh); WRK(0, kh0, kh1);
    qh  = *reinterpret_cast<const uint4*>(qp + CSTRIDE + t * 8);
    kh0 = *reinterpret_cast<const uint4*>(kp + CSTRIDE + t * 8);
    kh1 = *reinterpret_cast<const uint4*>(kp + CSTRIDE + (t + 512) * 8);
    __syncthreads();

#pragma unroll
    for (int ch = 0; ch < 12; ++ch) {
        const unsigned short* qbase = Qs + (ch & 1) * 5120 + dsub * 640;
        const unsigned short* kbase = Ks + (ch & 1) * 9216 + dsub * 1152;
        short8 a  = *reinterpret_cast<const short8*>(qbase + lr * 40 + hk * 8);
        short8 b0 = *reinterpret_cast<const short8*>(kbase + lr * 36 + hk * 8);
        short8 b1 = *reinterpret_cast<const short8*>(kbase + (16 + lr) * 36 + hk * 8);
        f32x4 s0 = __builtin_amdgcn_mfma_f32_16x16x32_bf16(a, b0, zero4, 0, 0, 0);
        f32x4 s1 = __builtin_amdgcn_mfma_f32_16x16x32_bf16(a, b1, zero4, 0, 0, 0);
        float e[8];
#pragma unroll
        for (int r = 0; r < 4; ++r) {
            e[r]     = __expf(s0[r] * scale + decv[r]);
            e[4 + r] = __expf(s1[r] * scale + decv[4 + r]);
        }
#pragma unroll
        for (int i = 0; i < 8; ++i) lacc[i] += e[i];
        ep[ch * 4 + 0] = cvtpk(e[0], e[1]);
        ep[ch * 4 + 1] = cvtpk(e[2], e[3]);
        ep[ch * 4 + 2] = cvtpk(e[4], e[5]);
        ep[ch * 4 + 3] = cvtpk(e[6], e[7]);
        if (ch < 11) {
            WRQ((ch + 1) & 1, qh); WRK((ch + 1) & 1, kh0, kh1);
            if (ch < 10) {
                qh  = *reinterpret_cast<const uint4*>(qp + (ch + 2) * CSTRIDE + t * 8);
                kh0 = *reinterpret_cast<const uint4*>(kp + (ch + 2) * CSTRIDE + t * 8);
                kh1 = *reinterpret_cast<const uint4*>(kp + (ch + 2) * CSTRIDE + (t + 512) * 8);
            }
        }
        __syncthreads();
    }

    // ---------------- l reduction (only cross-wave communication) ----------------
#pragma unroll
    for (int i = 0; i < 8; ++i)
        lred[dsub * 528 + (hk * 4 + (i & 3)) * 33 + (i >> 2) * 16 + lr] = lacc[i];
    __syncthreads();
    {
        float rsum = 0.f;
#pragma unroll
        for (int s = 0; s < 8; ++s) rsum += lred[s * 528 + (t >> 5) * 33 + (t & 31)];
        rlb[(t >> 5) * 33 + (t & 31)] = 1.0f / rsum;
    }
    __syncthreads();
    float rl8[8];
#pragma unroll
    for (int i = 0; i < 8; ++i)
        rl8[i] = rlb[(hk * 4 + (i & 3)) * 33 + (i >> 2) * 16 + lr];
    __syncthreads();

    // ---------------- PASS 2: P = E*rl (wave-local) -> PV -> out ----------------
    auto WRV = [&](int buf, uint4 v0, uint4 v1) {
        const unsigned short* s0 = (const unsigned short*)&v0;
        const unsigned short* s1 = (const unsigned short*)&v1;
        int a0 = buf * 9216 + (t & 31) * 36 + (t >> 5);
        int a1 = buf * 9216 + ((t + 512) & 31) * 36 + ((t + 512) >> 5);
#pragma unroll
        for (int i = 0; i < 8; ++i) { Vs[a0 + i * 1152] = s0[i]; Vs[a1 + i * 1152] = s1[i]; }
    };

    uint4 vh0 = *reinterpret_cast<const uint4*>(vp + t * 8);
    uint4 vh1 = *reinterpret_cast<const uint4*>(vp + (t + 512) * 8);
    WRV(0, vh0, vh1);
    vh0 = *reinterpret_cast<const uint4*>(vp + CSTRIDE + t * 8);
    vh1 = *reinterpret_cast<const uint4*>(vp + CSTRIDE + (t + 512) * 8);
    __syncthreads();

    unsigned short* Pb = (unsigned short*)(Osf + dsub * 528);   // aliases Os[dsub]
    size_t obase0 = ((size_t)(b * 64 + oc) * 1024 + half * 512 + t) * 96;

#pragma unroll
    for (int ch = 0; ch < 12; ++ch) {
        // build P in wave-private Pb (C-layout rows x stride 36)
#pragma unroll
        for (int gb = 0; gb < 2; ++gb)
#pragma unroll
            for (int rp = 0; rp < 2; ++rp) {
                unsigned int u = ep[ch * 4 + gb * 2 + rp];
                float p0 = __uint_as_float(u << 16)         * rl8[gb * 4 + rp * 2];
                float p1 = __uint_as_float(u & 0xffff0000u) * rl8[gb * 4 + rp * 2 + 1];
                unsigned int pk = cvtpk(p0, p1);
                Pb[(hk * 4 + rp * 2) * 36 + gb * 16 + lr]     = (unsigned short)pk;
                Pb[(hk * 4 + rp * 2 + 1) * 36 + gb * 16 + lr] = (unsigned short)(pk >> 16);
            }
        asm volatile("s_waitcnt lgkmcnt(0)" ::: "memory");
        __builtin_amdgcn_sched_barrier(0);
        short8 pa = *reinterpret_cast<const short8*>(Pb + lr * 36 + hk * 8);
        const unsigned short* vbase = Vs + (ch & 1) * 9216 + dsub * 1152;
        short8 vb0 = *reinterpret_cast<const short8*>(vbase + lr * 36 + hk * 8);
        short8 vb1 = *reinterpret_cast<const short8*>(vbase + (16 + lr) * 36 + hk * 8);
        f32x4 o0 = __builtin_amdgcn_mfma_f32_16x16x32_bf16(pa, vb0, zero4, 0, 0, 0);
        f32x4 o1 = __builtin_amdgcn_mfma_f32_16x16x32_bf16(pa, vb1, zero4, 0, 0, 0);
        if (ch < 11) {
            WRV((ch + 1) & 1, vh0, vh1);
            if (ch < 10) {
                vh0 = *reinterpret_cast<const uint4*>(vp + (ch + 2) * CSTRIDE + t * 8);
                vh1 = *reinterpret_cast<const uint4*>(vp + (ch + 2) * CSTRIDE + (t + 512) * 8);
            }
        }
#pragma unroll
        for (int r = 0; r < 4; ++r) {
            Osf[dsub * 528 + (hk * 4 + r) * 33 + lr]      = o0[r];
            Osf[dsub * 528 + (hk * 4 + r) * 33 + 16 + lr] = o1[r];
        }
        __syncthreads();
        {
            int lidx = (t >> 5) * 33 + (t & 31);
            float4 oA, oB;
            oA.x = Osf[0 * 528 + lidx]; oA.y = Osf[1 * 528 + lidx];
            oA.z = Osf[2 * 528 + lidx]; oA.w = Osf[3 * 528 + lidx];
            oB.x = Osf[4 * 528 + lidx]; oB.y = Osf[5 * 528 + lidx];
            oB.z = Osf[6 * 528 + lidx]; oB.w = Osf[7 * 528 + lidx];
            *reinterpret_cast<float4*>(out + obase0 + ch * 8)     = oA;
            *reinterpret_cast<float4*>(out + obase0 + ch * 8 + 4) = oB;
        }
        __syncthreads();
    }
}

extern "C" void kernel_launch(void* const* d_in, const int* in_sizes, int n_in,
                              void* d_out, int out_size, void* d_ws, size_t ws_size,
                              hipStream_t stream) {
    const float* x     = (const float*)d_in[0];
    const float* w_sr  = (const float*)d_in[1];
    const float* b_sr  = (const float*)d_in[2];
    const float* Wq    = (const float*)d_in[3];
    const float* bq    = (const float*)d_in[4];
    const float* Wkv   = (const float*)d_in[5];
    const float* bkv   = (const float*)d_in[6];
    const float* gamma = (const float*)d_in[7];
    const float* beta  = (const float*)d_in[8];
    float* out = (float*)d_out;

    unsigned short* qb = (unsigned short*)d_ws;
    unsigned short* kb = qb + (size_t)50331648;
    unsigned short* vb = kb + (size_t)50331648;

    proj_mfma<<<2048, 512, 0, stream>>>(x, w_sr, b_sr, Wq, bq, Wkv, bkv, qb, kb, vb);

    (void)hipFuncSetAttribute(reinterpret_cast<const void*>(attn_kernel),
                              hipFuncAttributeMaxDynamicSharedMemorySize, 57344);
    attn_kernel<<<1024, 512, 57344, stream>>>(qb, kb, vb, gamma, beta, out);
}

// Round 8
// 298.431 us; speedup vs baseline: 1.4638x; 1.1605x over previous
//
#include <hip/hip_runtime.h>
#include <stdint.h>
#include <stddef.h>

typedef __attribute__((ext_vector_type(8))) short short8;
typedef __attribute__((ext_vector_type(4))) float f32x4;

// ---- sizes ----
// x: (8, 64, 32, 32, 96) f32.  NH=4, hd=16, scale = 0.25
// intermediates q,k,v: bf16, per (b,o): layout [ch=d/8][pos=h*32+w][dl=d%8]
#define PER_BO 98304            // 12 * 8192 ushorts per (b,o)
#define CSTRIDE 8192            // 1024 pos * 8 dl

__device__ __forceinline__ unsigned int cvtpk(float lo, float hi) {
    unsigned int r;
    asm("v_cvt_pk_bf16_f32 %0, %1, %2" : "=v"(r) : "v"(lo), "v"(hi));
    return r;
}

// ============================ Kernel 1: projection GEMM (MFMA) ============================
// (unchanged from round 6 — C routed through LDS, coalesced stream-out)
__global__ __launch_bounds__(512, 2) void proj_mfma(
    const float* __restrict__ x, const float* __restrict__ w_sr, const float* __restrict__ b_sr,
    const float* __restrict__ Wq, const float* __restrict__ bq,
    const float* __restrict__ Wkv, const float* __restrict__ bkv,
    unsigned short* __restrict__ qb, unsigned short* __restrict__ kb, unsigned short* __restrict__ vb)
{
    __shared__ unsigned short Wh[12288];
    __shared__ float bl[192];
    __shared__ unsigned short Cb[2 * 6464];

    int t = threadIdx.x;
    int bidx = blockIdx.x;
    int b = bidx >> 8;
    int blk = bidx & 255;

    int lane = t & 63;
    int wvi = t >> 6;
    int lr = lane & 15, hk = lane >> 4;

    const float* xb = x + (size_t)b * 6291456 + (size_t)blk * 384;
    float af[3][16];
#pragma unroll
    for (int pi = 0; pi < 3; ++pi) {
        int pt = wvi * 3 + pi;
        const float* xp = xb + (size_t)(hk * 8) * 98304 + pt * 16 + lr;
#pragma unroll
        for (int j = 0; j < 8; ++j) {
            af[pi][j]     = xp[(size_t)j * 98304];
            af[pi][8 + j] = xp[(size_t)(32 + j) * 98304];
        }
    }

#pragma unroll
    for (int i = 0; i < 6; ++i) {
        int qi = t + i * 512;
        int o = qi >> 4;
        int cq = qi & 15;
        int c = cq * 4;
        float4 wv4;
        if (o < 64) wv4 = *reinterpret_cast<const float4*>(Wq + o * 64 + c);
        else {
            wv4 = *reinterpret_cast<const float4*>(Wkv + (o - 64) * 64 + c);
            float4 sr = *reinterpret_cast<const float4*>(w_sr + c);
            wv4.x *= sr.x; wv4.y *= sr.y; wv4.z *= sr.z; wv4.w *= sr.w;
        }
        uint2 pk; pk.x = cvtpk(wv4.x, wv4.y); pk.y = cvtpk(wv4.z, wv4.w);
        int sw = (cq >> 1) ^ (o & 7);
        *reinterpret_cast<uint2*>(&Wh[o * 64 + sw * 8 + (cq & 1) * 4]) = pk;
    }
    if (t < 192) {
        float s;
        if (t < 64) s = bq[t];
        else {
            s = bkv[t - 64];
            for (int c = 0; c < 64; ++c) s += Wkv[(t - 64) * 64 + c] * b_sr[c];
        }
        bl[t] = s;
    }
    __syncthreads();

    short8 ahf[3][2], alf[3][2];
#pragma unroll
    for (int pi = 0; pi < 3; ++pi) {
#pragma unroll
        for (int half = 0; half < 2; ++half) {
            union { unsigned int u[4]; short8 v; } H, L;
#pragma unroll
            for (int q = 0; q < 4; ++q) {
                float f0 = af[pi][half * 8 + 2 * q];
                float f1 = af[pi][half * 8 + 2 * q + 1];
                unsigned int hp = cvtpk(f0, f1);
                float h0 = __uint_as_float(hp << 16);
                float h1 = __uint_as_float(hp & 0xffff0000u);
                H.u[q] = hp;
                L.u[q] = cvtpk(f0 - h0, f1 - h1);
            }
            ahf[pi][half] = H.v; alf[pi][half] = L.v;
        }
    }

    int wo[3];
#pragma unroll
    for (int pi = 0; pi < 3; ++pi) {
        int p0 = (wvi * 3 + pi) * 16 + hk * 4;
        int hwl = p0 / 96;
        int d0 = p0 - hwl * 96;
        wo[pi] = lr * 404 + hwl * 100 + d0;
    }

    int so_po[3], so_lo[3];
#pragma unroll
    for (int i = 0; i < 3; ++i) {
        int flat = i * 512 + t;
        int dlq = flat & 1;
        int hwl = (flat >> 1) & 3;
        int ch  = (flat >> 3) % 12;
        int o   = flat / 96;
        so_po[i] = o * PER_BO + ch * 8192 + (blk * 4 + hwl) * 8 + dlq * 4;
        so_lo[i] = o * 404 + hwl * 100 + ch * 8 + dlq * 4;
    }

    float biasv[12];
#pragma unroll
    for (int ot = 0; ot < 12; ++ot) biasv[ot] = bl[ot * 16 + lr];

    f32x4 zero4 = {0.f, 0.f, 0.f, 0.f};
    int s7 = lr & 7;

#pragma unroll
    for (int ot = 0; ot < 12; ++ot) {
        unsigned short* cb = Cb + (ot & 1) * 6464;
        {
            int o = ot * 16 + lr;
            const unsigned short* wr = &Wh[o * 64];
            short8 b0 = *reinterpret_cast<const short8*>(wr + ((hk ^ s7) * 8));
            short8 b1 = *reinterpret_cast<const short8*>(wr + (((hk + 4) ^ s7) * 8));
            float bo = biasv[ot];
#pragma unroll
            for (int pi = 0; pi < 3; ++pi) {
                f32x4 acc = __builtin_amdgcn_mfma_f32_16x16x32_bf16(ahf[pi][0], b0, zero4, 0, 0, 0);
                acc = __builtin_amdgcn_mfma_f32_16x16x32_bf16(ahf[pi][1], b1, acc, 0, 0, 0);
                acc = __builtin_amdgcn_mfma_f32_16x16x32_bf16(alf[pi][0], b0, acc, 0, 0, 0);
                acc = __builtin_amdgcn_mfma_f32_16x16x32_bf16(alf[pi][1], b1, acc, 0, 0, 0);
                uint2 st;
                st.x = cvtpk(acc[0] + bo, acc[1] + bo);
                st.y = cvtpk(acc[2] + bo, acc[3] + bo);
                *reinterpret_cast<uint2*>(&cb[wo[pi]]) = st;
            }
        }
        __syncthreads();
        {
            int sel = ot >> 2;
            unsigned short* base =
                (sel == 0 ? qb : (sel == 1 ? kb : vb)) + (size_t)(b * 64 + (ot & 3) * 16) * PER_BO;
#pragma unroll
            for (int i = 0; i < 3; ++i)
                *reinterpret_cast<uint2*>(base + so_po[i]) =
                    *reinterpret_cast<const uint2*>(&cb[so_lo[i]]);
        }
    }
}

// ============================ Kernel 2: attention (d-sliced waves) ============================
// Block = (b, oc, h-half) via XCD pair-swizzle: both halves of a (b,oc) pair land on the same
// XCD's L2 (shared K/V). 512 threads = 8 waves; wave dsub owns depth dl=dsub of each chunk.
// E kept in 48 packed-bf16 VGPRs. Out writes paired: 64B (full line) per thread per 2 ch.
// LDS 52224 B (3 blocks/CU): Qs 2x8704B @0, Ks 2x17408B @17408;
//   lred 8x528 f32 @0, rlb @16896; Vs 2x17408B @0, Osf 8x528 f32 @34816 (Pb aliases Osf[dsub]).
__global__ __launch_bounds__(512, 4) void attn_kernel(
    const unsigned short* __restrict__ qb, const unsigned short* __restrict__ kb,
    const unsigned short* __restrict__ vb,
    const float* __restrict__ gamma, const float* __restrict__ beta,
    float* __restrict__ out)
{
    extern __shared__ char smem[];
    unsigned short* Qs = (unsigned short*)smem;
    unsigned short* Ks = (unsigned short*)(smem + 17408);
    float* lred = (float*)smem;
    float* rlb  = (float*)(smem + 16896);
    unsigned short* Vs = (unsigned short*)smem;
    float* Osf  = (float*)(smem + 34816);

    int t = threadIdx.x;
    int l = t & 63;
    int dsub = t >> 6;                 // wave id = owned dl
    int lr = l & 15, hk = l >> 4;

    // XCD pair swizzle: id%8 = XCD (dispatch round-robin); pair p gets both halves on one XCD.
    int id = blockIdx.x;
    int xcd = id & 7;
    int k7 = id >> 3;                  // 0..127
    int p = xcd + 8 * (k7 >> 1);       // pair 0..511
    int half = k7 & 1;
    int oc = p & 63;
    int b = p >> 6;
    int n = oc >> 4;

    const unsigned short* qp = qb + (size_t)(b * 64 + oc) * PER_BO + half * 4096;
    const unsigned short* kp = kb + (size_t)(b * 64 + oc) * PER_BO;
    const unsigned short* vp = vb + (size_t)(b * 64 + oc) * PER_BO;

    float gm = gamma[n], bt = beta[n];
    float decv[8];                     // [gb*4 + r]
#pragma unroll
    for (int gb = 0; gb < 2; ++gb)
#pragma unroll
        for (int r = 0; r < 4; ++r) {
            int hh = half * 16 + hk * 4 + r;
            int gg = gb * 16 + lr;
            float dc = 2.0f * fabsf((float)(hh - gg)) * gm + bt;
            float sp = fmaxf(dc, 0.0f) + log1pf(__expf(-fabsf(dc)));
            decv[gb * 4 + r] = __expf(-sp);
        }

    const float scale = 0.25f;
    f32x4 zero4 = {0.f, 0.f, 0.f, 0.f};

    unsigned int ep[48];
    float lacc[8] = {0.f, 0.f, 0.f, 0.f, 0.f, 0.f, 0.f, 0.f};

    auto WRQ = [&](int buf, uint4 v) {
        const unsigned short* sq = (const unsigned short*)&v;
        int base = buf * 4352 + (t >> 5) * 34 + (t & 31);
#pragma unroll
        for (int i = 0; i < 8; ++i) Qs[base + i * 544] = sq[i];
    };
    auto WRK = [&](int buf, uint4 v0, uint4 v1) {
        const unsigned short* s0 = (const unsigned short*)&v0;
        const unsigned short* s1 = (const unsigned short*)&v1;
        int b0 = buf * 8704 + (t >> 5) * 34 + (t & 31);
        int b1 = buf * 8704 + ((t + 512) >> 5) * 34 + (t & 31);
#pragma unroll
        for (int i = 0; i < 8; ++i) { Ks[b0 + i * 1088] = s0[i]; Ks[b1 + i * 1088] = s1[i]; }
    };

    // ---------------- PASS 1: QK^T -> E (regs) + partial l ----------------
    uint4 qh  = *reinterpret_cast<const uint4*>(qp + t * 8);
    uint4 kh0 = *reinterpret_cast<const uint4*>(kp + t * 8);
    uint4 kh1 = *reinterpret_cast<const uint4*>(kp + (t + 512) * 8);
    WRQ(0, qh); WRK(0, kh0, kh1);
    qh  = *reinterpret_cast<const uint4*>(qp + CSTRIDE + t * 8);
    kh0 = *reinterpret_cast<const uint4*>(kp + CSTRIDE + t * 8);
    kh1 = *reinterpret_cast<const uint4*>(kp + CSTRIDE + (t + 512) * 8);
    __syncthreads();

#pragma unroll
    for (int ch = 0; ch < 12; ++ch) {
        const unsigned short* qbase = Qs + (ch & 1) * 4352 + dsub * 544;
        const unsigned short* kbase = Ks + (ch & 1) * 8704 + dsub * 1088;
        short8 a  = *reinterpret_cast<const short8*>(qbase + lr * 34 + hk * 8);
        short8 b0 = *reinterpret_cast<const short8*>(kbase + lr * 34 + hk * 8);
        short8 b1 = *reinterpret_cast<const short8*>(kbase + (16 + lr) * 34 + hk * 8);
        f32x4 s0 = __builtin_amdgcn_mfma_f32_16x16x32_bf16(a, b0, zero4, 0, 0, 0);
        f32x4 s1 = __builtin_amdgcn_mfma_f32_16x16x32_bf16(a, b1, zero4, 0, 0, 0);
        float e[8];
#pragma unroll
        for (int r = 0; r < 4; ++r) {
            e[r]     = __expf(s0[r] * scale + decv[r]);
            e[4 + r] = __expf(s1[r] * scale + decv[4 + r]);
        }
#pragma unroll
        for (int i = 0; i < 8; ++i) lacc[i] += e[i];
        ep[ch * 4 + 0] = cvtpk(e[0], e[1]);
        ep[ch * 4 + 1] = cvtpk(e[2], e[3]);
        ep[ch * 4 + 2] = cvtpk(e[4], e[5]);
        ep[ch * 4 + 3] = cvtpk(e[6], e[7]);
        if (ch < 11) {
            WRQ((ch + 1) & 1, qh); WRK((ch + 1) & 1, kh0, kh1);
            if (ch < 10) {
                qh  = *reinterpret_cast<const uint4*>(qp + (ch + 2) * CSTRIDE + t * 8);
                kh0 = *reinterpret_cast<const uint4*>(kp + (ch + 2) * CSTRIDE + t * 8);
                kh1 = *reinterpret_cast<const uint4*>(kp + (ch + 2) * CSTRIDE + (t + 512) * 8);
            }
        }
        __syncthreads();
    }

    // ---------------- l reduction (only cross-wave communication) ----------------
#pragma unroll
    for (int i = 0; i < 8; ++i)
        lred[dsub * 528 + (hk * 4 + (i & 3)) * 33 + (i >> 2) * 16 + lr] = lacc[i];
    __syncthreads();
    {
        float rsum = 0.f;
#pragma unroll
        for (int s = 0; s < 8; ++s) rsum += lred[s * 528 + (t >> 5) * 33 + (t & 31)];
        rlb[(t >> 5) * 33 + (t & 31)] = 1.0f / rsum;
    }
    __syncthreads();
    float rl8[8];
#pragma unroll
    for (int i = 0; i < 8; ++i)
        rl8[i] = rlb[(hk * 4 + (i & 3)) * 33 + (i >> 2) * 16 + lr];
    __syncthreads();

    // ---------------- PASS 2: P = E*rl (wave-local) -> PV -> out (64B paired) ----------------
    auto WRV = [&](int buf, uint4 v0, uint4 v1) {
        const unsigned short* s0 = (const unsigned short*)&v0;
        const unsigned short* s1 = (const unsigned short*)&v1;
        int a0 = buf * 8704 + (t & 31) * 34 + (t >> 5);
        int a1 = buf * 8704 + (t & 31) * 34 + (t >> 5) + 16;
#pragma unroll
        for (int i = 0; i < 8; ++i) { Vs[a0 + i * 1088] = s0[i]; Vs[a1 + i * 1088] = s1[i]; }
    };

    uint4 vh0 = *reinterpret_cast<const uint4*>(vp + t * 8);
    uint4 vh1 = *reinterpret_cast<const uint4*>(vp + (t + 512) * 8);
    WRV(0, vh0, vh1);
    vh0 = *reinterpret_cast<const uint4*>(vp + CSTRIDE + t * 8);
    vh1 = *reinterpret_cast<const uint4*>(vp + CSTRIDE + (t + 512) * 8);
    __syncthreads();

    unsigned short* Pb = (unsigned short*)(Osf + dsub * 528);   // aliases Osf[dsub]
    size_t obase0 = ((size_t)(b * 64 + oc) * 1024 + half * 512 + t) * 96;
    float4 hA, hB;

#pragma unroll
    for (int ch = 0; ch < 12; ++ch) {
        // build P in wave-private Pb (C-layout rows, stride 36)
#pragma unroll
        for (int gb = 0; gb < 2; ++gb)
#pragma unroll
            for (int rp = 0; rp < 2; ++rp) {
                unsigned int u = ep[ch * 4 + gb * 2 + rp];
                float p0 = __uint_as_float(u << 16)         * rl8[gb * 4 + rp * 2];
                float p1 = __uint_as_float(u & 0xffff0000u) * rl8[gb * 4 + rp * 2 + 1];
                unsigned int pk = cvtpk(p0, p1);
                Pb[(hk * 4 + rp * 2) * 36 + gb * 16 + lr]     = (unsigned short)pk;
                Pb[(hk * 4 + rp * 2 + 1) * 36 + gb * 16 + lr] = (unsigned short)(pk >> 16);
            }
        asm volatile("s_waitcnt lgkmcnt(0)" ::: "memory");
        __builtin_amdgcn_sched_barrier(0);
        short8 pa = *reinterpret_cast<const short8*>(Pb + lr * 36 + hk * 8);
        const unsigned short* vbase = Vs + (ch & 1) * 8704 + dsub * 1088;
        short8 vb0 = *reinterpret_cast<const short8*>(vbase + lr * 34 + hk * 8);
        short8 vb1 = *reinterpret_cast<const short8*>(vbase + (16 + lr) * 34 + hk * 8);
        f32x4 o0 = __builtin_amdgcn_mfma_f32_16x16x32_bf16(pa, vb0, zero4, 0, 0, 0);
        f32x4 o1 = __builtin_amdgcn_mfma_f32_16x16x32_bf16(pa, vb1, zero4, 0, 0, 0);
        if (ch < 11) {
            WRV((ch + 1) & 1, vh0, vh1);
            if (ch < 10) {
                vh0 = *reinterpret_cast<const uint4*>(vp + (ch + 2) * CSTRIDE + t * 8);
                vh1 = *reinterpret_cast<const uint4*>(vp + (ch + 2) * CSTRIDE + (t + 512) * 8);
            }
        }
#pragma unroll
        for (int r = 0; r < 4; ++r) {
            Osf[dsub * 528 + (hk * 4 + r) * 33 + lr]      = o0[r];
            Osf[dsub * 528 + (hk * 4 + r) * 33 + 16 + lr] = o1[r];
        }
        __syncthreads();
        {
            int lidx = (t >> 5) * 33 + (t & 31);
            float4 cA, cB;
            cA.x = Osf[0 * 528 + lidx]; cA.y = Osf[1 * 528 + lidx];
            cA.z = Osf[2 * 528 + lidx]; cA.w = Osf[3 * 528 + lidx];
            cB.x = Osf[4 * 528 + lidx]; cB.y = Osf[5 * 528 + lidx];
            cB.z = Osf[6 * 528 + lidx]; cB.w = Osf[7 * 528 + lidx];
            if ((ch & 1) == 0) { hA = cA; hB = cB; }
            else {
                float* po = out + obase0 + (ch >> 1) * 16;
                *reinterpret_cast<float4*>(po)      = hA;
                *reinterpret_cast<float4*>(po + 4)  = hB;
                *reinterpret_cast<float4*>(po + 8)  = cA;
                *reinterpret_cast<float4*>(po + 12) = cB;
            }
        }
        __syncthreads();
    }
}

extern "C" void kernel_launch(void* const* d_in, const int* in_sizes, int n_in,
                              void* d_out, int out_size, void* d_ws, size_t ws_size,
                              hipStream_t stream) {
    const float* x     = (const float*)d_in[0];
    const float* w_sr  = (const float*)d_in[1];
    const float* b_sr  = (const float*)d_in[2];
    const float* Wq    = (const float*)d_in[3];
    const float* bq    = (const float*)d_in[4];
    const float* Wkv   = (const float*)d_in[5];
    const float* bkv   = (const float*)d_in[6];
    const float* gamma = (const float*)d_in[7];
    const float* beta  = (const float*)d_in[8];
    float* out = (float*)d_out;

    unsigned short* qb = (unsigned short*)d_ws;
    unsigned short* kb = qb + (size_t)50331648;
    unsigned short* vb = kb + (size_t)50331648;

    proj_mfma<<<2048, 512, 0, stream>>>(x, w_sr, b_sr, Wq, bq, Wkv, bkv, qb, kb, vb);

    (void)hipFuncSetAttribute(reinterpret_cast<const void*>(attn_kernel),
                              hipFuncAttributeMaxDynamicSharedMemorySize, 52224);
    attn_kernel<<<1024, 512, 52224, stream>>>(qb, kb, vb, gamma, beta, out);
}